// Round 3
// baseline (372.791 us; speedup 1.0000x reference)
//
#include <hip/hip_runtime.h>
#include <hip/hip_bf16.h>
#include <math.h>

typedef __bf16 bf16x8 __attribute__((ext_vector_type(8)));
typedef float f32x4 __attribute__((ext_vector_type(4)));

#define CDIM 128

// Runtime-dtype float load: f32 ? float* : bf16*
__device__ __forceinline__ float load_flt(const void* p, size_t i, int f32) {
  return f32 ? ((const float*)p)[i] : (float)(((const __hip_bfloat16*)p)[i]);
}

// ---------------- dtype sniff: view w1 as bf16; f32 data shows huge values ----
__global__ __launch_bounds__(256) void sniff_kernel(const void* w, int* flag) {
  __shared__ int cnt;
  if (threadIdx.x == 0) cnt = 0;
  __syncthreads();
  const __hip_bfloat16* p = (const __hip_bfloat16*)w;
  int c = 0;
  for (int i = threadIdx.x; i < 8192; i += 256) {
    float v = (float)p[i];
    if (!(fabsf(v) <= 100.f)) c++;   // catches big AND NaN
  }
  atomicAdd(&cnt, c);
  __syncthreads();
  if (threadIdx.x == 0) flag[0] = (cnt > 0) ? 1 : 0;  // 1 => inputs are float32
}

__global__ void sentinel_kernel(float* outf) {
  if (threadIdx.x == 0) outf[0] = 12345.0f;  // ws_size too small signature
}

// ---------------- small utility kernels ----------------

__global__ __launch_bounds__(128) void consts_kernel(
    const void* le1, const void* e1, const void* le2, const void* e2,
    float* __restrict__ outc, const int* __restrict__ flag) {
  __shared__ float s1[CDIM], s2[CDIM];
  int f = flag[0];
  int t = threadIdx.x;
  s1[t] = load_flt(le1, t, f) * load_flt(e1, t, f);
  s2[t] = load_flt(le2, t, f) * load_flt(e2, t, f);
  __syncthreads();
  for (int off = 64; off > 0; off >>= 1) {
    if (t < off) { s1[t] += s1[t + off]; s2[t] += s2[t + off]; }
    __syncthreads();
  }
  if (t == 0) { outc[0] = s1[0]; outc[1] = s2[0]; }
}

__global__ __launch_bounds__(256) void hist_kernel(const int* __restrict__ dstv,
                                                   int* __restrict__ deg, int E) {
  int e = blockIdx.x * 256 + threadIdx.x;
  if (e < E) atomicAdd(&deg[dstv[e]], 1);
}

__global__ __launch_bounds__(256) void scan1_kernel(const int* __restrict__ deg,
                                                    int* __restrict__ rowptr,
                                                    int* __restrict__ partials, int n) {
  __shared__ int sh[256];
  int t = threadIdx.x;
  int base = blockIdx.x * 1024;
  int idx = base + t * 4;
  int v[4]; int s = 0;
#pragma unroll
  for (int j = 0; j < 4; ++j) { v[j] = (idx + j < n) ? deg[idx + j] : 0; s += v[j]; }
  sh[t] = s;
  __syncthreads();
  for (int off = 1; off < 256; off <<= 1) {
    int x = (t >= off) ? sh[t - off] : 0;
    __syncthreads();
    sh[t] += x;
    __syncthreads();
  }
  int excl = sh[t] - s;
  if (t == 255) partials[blockIdx.x] = sh[255];
  int run = excl;
#pragma unroll
  for (int j = 0; j < 4; ++j) {
    if (idx + j < n) rowptr[idx + j] = run;
    run += v[j];
  }
}

__global__ void scan2_kernel(int* __restrict__ partials, int nb) {
  if (threadIdx.x == 0 && blockIdx.x == 0) {
    int run = 0;
    for (int i = 0; i < nb; ++i) { int t = partials[i]; partials[i] = run; run += t; }
  }
}

__global__ __launch_bounds__(256) void scan3_kernel(int* __restrict__ rowptr,
                                                    int* __restrict__ cursor,
                                                    const int* __restrict__ partials,
                                                    int n, int E) {
  int i = blockIdx.x * 256 + threadIdx.x;
  if (i < n) {
    int v = rowptr[i] + partials[i >> 10];
    rowptr[i] = v;
    cursor[i] = v;
  } else if (i == n) {
    rowptr[n] = E;
  }
}

__global__ __launch_bounds__(256) void scatter_kernel(
    const int* __restrict__ srcv, const int* __restrict__ dstv,
    const int* __restrict__ etype, const void* eattr,
    int* __restrict__ cursor, int* __restrict__ key, float* __restrict__ attrp,
    int E, int n, const int* __restrict__ flag) {
  int e = blockIdx.x * 256 + threadIdx.x;
  if (e >= E) return;
  int f = flag[0];
  int p = atomicAdd(&cursor[dstv[e]], 1);
  key[p] = etype[e] * n + srcv[e];
  attrp[p] = load_flt(eattr, e, f);
}

// wt[r][kb][o][j] = w[r][kb*8+j][o]  (B^T tile layout for MFMA b-frags)
__global__ __launch_bounds__(256) void transpose_w_kernel(
    const void* w, __hip_bfloat16* __restrict__ wt, int total,
    const int* __restrict__ flag) {
  int t = blockIdx.x * 256 + threadIdx.x;
  if (t >= total) return;            // total = R*16*128
  int f = flag[0];
  int r = t >> 11;
  int rem = t & 2047;
  int kb = rem >> 7;
  int o = rem & 127;
  size_t rbase = (size_t)r << 14;
  union { __hip_bfloat16 h[8]; int4 v; } u;
#pragma unroll
  for (int j = 0; j < 8; ++j)
    u.h[j] = __float2bfloat16(load_flt(w, rbase + (size_t)(kb * 8 + j) * CDIM + o, f));
  *reinterpret_cast<int4*>(wt + (size_t)t * 8) = u.v;
}

// ---------------- GEMM: xw[r] = xin @ w[r]; also sq[r,n]=xw.q, sk[r,n]=xw.k ----
__global__ __launch_bounds__(256) void gemm_xw_kernel(
    const void* xin, int xin_mode,  // 0: always bf16; 1: follow dtype flag
    const __hip_bfloat16* __restrict__ wt,
    const void* qv, const void* kv,
    __hip_bfloat16* __restrict__ xwout, float* __restrict__ sq, float* __restrict__ sk,
    int n, const int* __restrict__ flag) {
  __shared__ __hip_bfloat16 wlds[16 * 128 * 8];  // 32 KB
  const int pf32 = flag[0];
  const int xf32 = xin_mode ? pf32 : 0;
  const int r = blockIdx.y;
  const int base = blockIdx.x * 128;
  const int tid = threadIdx.x;
  {
    const int4* src = reinterpret_cast<const int4*>(wt + ((size_t)r << 14));
    int4* dst = reinterpret_cast<int4*>(wlds);
    for (int i = tid; i < 2048; i += 256) dst[i] = src[i];
  }
  __syncthreads();

  const int wave = tid >> 6, lane = tid & 63;
  const int quad = lane >> 4, c16 = lane & 15;

  bf16x8 zf;
#pragma unroll
  for (int j = 0; j < 8; ++j) zf[j] = (__bf16)0.0f;

  bf16x8 af[2][4];
#pragma unroll
  for (int h = 0; h < 2; ++h) {
    int m = base + wave * 32 + h * 16 + c16;
#pragma unroll
    for (int ks = 0; ks < 4; ++ks) {
      if (m < n) {
        size_t off = (size_t)m * CDIM + ks * 32 + quad * 8;
        if (xf32) {
          const float* xp = (const float*)xin + off;
          bf16x8 a;
#pragma unroll
          for (int j = 0; j < 8; ++j) a[j] = (__bf16)xp[j];
          af[h][ks] = a;
        } else {
          af[h][ks] = *reinterpret_cast<const bf16x8*>((const __hip_bfloat16*)xin + off);
        }
      } else {
        af[h][ks] = zf;
      }
    }
  }

  f32x4 acc[2][8];
#pragma unroll
  for (int h = 0; h < 2; ++h)
#pragma unroll
    for (int nt = 0; nt < 8; ++nt) acc[h][nt] = (f32x4){0.f, 0.f, 0.f, 0.f};

#pragma unroll
  for (int ks = 0; ks < 4; ++ks) {
#pragma unroll
    for (int nt = 0; nt < 8; ++nt) {
      bf16x8 b = *reinterpret_cast<const bf16x8*>(
          &wlds[(((ks * 4 + quad) * 128) + nt * 16 + c16) * 8]);
      acc[0][nt] = __builtin_amdgcn_mfma_f32_16x16x32_bf16(af[0][ks], b, acc[0][nt], 0, 0, 0);
      acc[1][nt] = __builtin_amdgcn_mfma_f32_16x16x32_bf16(af[1][ks], b, acc[1][nt], 0, 0, 0);
    }
  }

  float qf[8], kf[8];
#pragma unroll
  for (int nt = 0; nt < 8; ++nt) {
    qf[nt] = load_flt(qv, nt * 16 + c16, pf32);
    kf[nt] = load_flt(kv, nt * 16 + c16, pf32);
  }

#pragma unroll
  for (int h = 0; h < 2; ++h) {
    int rowb = base + wave * 32 + h * 16 + quad * 4;
#pragma unroll
    for (int reg = 0; reg < 4; ++reg) {
      int grow = rowb + reg;
      float s_q = 0.f, s_k = 0.f;
#pragma unroll
      for (int nt = 0; nt < 8; ++nt) {
        float v = acc[h][nt][reg];
        float vs = isfinite(v) ? v : 20000.0f;  // diagnostic tag: gemm NaN
        if (grow < n)
          xwout[(((size_t)r * n + grow) << 7) + nt * 16 + c16] = __float2bfloat16(vs);
        s_q += v * qf[nt];
        s_k += v * kf[nt];
      }
#pragma unroll
      for (int off = 1; off < 16; off <<= 1) {
        s_q += __shfl_xor(s_q, off, 64);
        s_k += __shfl_xor(s_k, off, 64);
      }
      if (c16 == 0 && grow < n) {
        sq[r * n + grow] = s_q;
        sk[r * n + grow] = s_k;
      }
    }
  }
}

// ---------------- per-node softmax + aggregation: one wave64 per node ----------
__global__ __launch_bounds__(256) void aggregate_kernel(
    const int* __restrict__ rowptr, const int* __restrict__ key,
    const float* __restrict__ attrp, const float* __restrict__ sq,
    const float* __restrict__ sk, const __hip_bfloat16* __restrict__ xw,
    const void* bias, const float* __restrict__ cscal,
    void* outp, int n, int do_relu,
    int out_mode,  // 0: always bf16 (hidden); 1: follow dtype flag
    const int* __restrict__ flag) {
  int node = blockIdx.x * 4 + (threadIdx.x >> 6);
  if (node >= n) return;
  int f = flag[0];
  int lane = threadIdx.x & 63;
  int start = rowptr[node];
  int end = rowptr[node + 1];
  float c = cscal[0];
  int n2 = n * 2;
  int n3 = n * 3;

  // pass 1: running max of leaky-relu logits (lane-parallel)
  float m = -__builtin_inff();
  for (int p = start + lane; p < end; p += 64) {
    int kk = key[p];
    kk = (kk < 0) ? 0 : (kk >= n3 ? n3 - 1 : kk);
    int et = (kk >= n2) ? 2 : ((kk >= n) ? 1 : 0);
    float l = sq[et * n + node] + sk[kk] + c * attrp[p];
    l = l > 0.f ? l : 0.2f * l;
    m = fmaxf(m, l);
  }
#pragma unroll
  for (int off = 32; off > 0; off >>= 1) m = fmaxf(m, __shfl_xor(m, off, 64));

  // pass 2: serial over edges; broadcast weight, coalesced feature load
  float acc0 = 0.f, acc1 = 0.f, den = 0.f;
  for (int p = start; p < end; ++p) {
    int kk = key[p];
    kk = (kk < 0) ? 0 : (kk >= n3 ? n3 - 1 : kk);
    int et = (kk >= n2) ? 2 : ((kk >= n) ? 1 : 0);
    float l = sq[et * n + node] + sk[kk] + c * attrp[p];
    l = l > 0.f ? l : 0.2f * l;
    float w = __expf(l - m);
    float f0 = (float)xw[(size_t)kk * CDIM + lane];
    float f1 = (float)xw[(size_t)kk * CDIM + 64 + lane];
    acc0 += w * f0;
    acc1 += w * f1;
    den += w;
  }
  float inv = 1.0f / (den + 1e-16f);
  float o0 = acc0 * inv + load_flt(bias, lane, f);
  float o1 = acc1 * inv + load_flt(bias, lane + 64, f);
  if (do_relu) { o0 = fmaxf(o0, 0.f); o1 = fmaxf(o1, 0.f); }
  if (!isfinite(o0)) o0 = 31337.0f;  // diagnostic tag: aggregate NaN
  if (!isfinite(o1)) o1 = 31337.0f;
  size_t i0 = (size_t)node * CDIM + lane;
  size_t i1 = i0 + 64;
  if (out_mode && f) {
    ((float*)outp)[i0] = o0;
    ((float*)outp)[i1] = o1;
  } else {
    ((__hip_bfloat16*)outp)[i0] = __float2bfloat16(o0);
    ((__hip_bfloat16*)outp)[i1] = __float2bfloat16(o1);
  }
}

// ---------------- launcher ----------------

extern "C" void kernel_launch(void* const* d_in, const int* in_sizes, int n_in,
                              void* d_out, int out_size, void* d_ws, size_t ws_size,
                              hipStream_t stream) {
  const void* x     = d_in[0];
  const int*  eidx  = (const int*)d_in[1];
  const int*  etype = (const int*)d_in[2];
  const void* eattr = d_in[3];
  const void* w1  = d_in[4];
  const void* q1  = d_in[5];
  const void* k1  = d_in[6];
  const void* le1 = d_in[7];
  const void* e1  = d_in[8];
  const void* b1  = d_in[9];
  const void* w2  = d_in[10];
  const void* q2  = d_in[11];
  const void* k2  = d_in[12];
  const void* le2 = d_in[13];
  const void* e2  = d_in[14];
  const void* b2  = d_in[15];

  const int N = in_sizes[0] / CDIM;           // 50000
  const int E = in_sizes[2];                  // 500000
  const int R = in_sizes[4] / (CDIM * CDIM);  // 3
  const int* srcv = eidx;
  const int* dstv = eidx + E;

  // ---- workspace partition ----
  char* p = (char*)d_ws;
  auto alloc = [&](size_t bytes) -> void* {
    void* q = (void*)p;
    p += (bytes + 255) & ~(size_t)255;
    return q;
  };
  float* sq       = (float*)alloc((size_t)R * N * 4);
  float* sk       = (float*)alloc((size_t)R * N * 4);
  int*   deg      = (int*)alloc((size_t)N * 4);
  int*   rowptr   = (int*)alloc((size_t)(N + 1) * 4);
  int*   cursor   = (int*)alloc((size_t)N * 4);
  int*   partials = (int*)alloc(4096);
  int*   key      = (int*)alloc((size_t)E * 4);
  float* attrp    = (float*)alloc((size_t)E * 4);
  __hip_bfloat16* wt = (__hip_bfloat16*)alloc((size_t)R * CDIM * CDIM * 2);
  float* cscal    = (float*)alloc(256);
  int*   dflag    = (int*)alloc(256);
  __hip_bfloat16* xw = (__hip_bfloat16*)alloc((size_t)R * N * CDIM * 2);

  size_t needed = (size_t)(p - (char*)d_ws);
  if (needed > ws_size) {
    // workspace too small: distinctive absmax signature 12345
    sentinel_kernel<<<1, 64, 0, stream>>>((float*)d_out);
    return;
  }

  __hip_bfloat16* hbuf = (__hip_bfloat16*)d_out;  // conv1 hidden lives in d_out

  const int eg = (E + 255) / 256;
  const int nb = (N + 1023) / 1024;
  const int nodes4 = (N + 3) / 4;

  // dtype sniff (w1 viewed as bf16: f32 data shows |v|>100 from mantissa halves)
  sniff_kernel<<<1, 256, 0, stream>>>(w1, dflag);

  // constants c = le . e  (both convs)
  consts_kernel<<<1, 128, 0, stream>>>(le1, e1, le2, e2, cscal, dflag);

  // CSR build (shared by both convs)
  hipMemsetAsync(deg, 0, (size_t)N * 4, stream);
  hist_kernel<<<eg, 256, 0, stream>>>(dstv, deg, E);
  scan1_kernel<<<nb, 256, 0, stream>>>(deg, rowptr, partials, N);
  scan2_kernel<<<1, 64, 0, stream>>>(partials, nb);
  scan3_kernel<<<(N + 1 + 255) / 256, 256, 0, stream>>>(rowptr, cursor, partials, N, E);
  scatter_kernel<<<eg, 256, 0, stream>>>(srcv, dstv, etype, eattr, cursor, key, attrp,
                                         E, N, dflag);

  dim3 ggrid((N + 127) / 128, R);

  // ---- conv1 ----
  transpose_w_kernel<<<(R * 2048 + 255) / 256, 256, 0, stream>>>(w1, wt, R * 2048, dflag);
  gemm_xw_kernel<<<ggrid, 256, 0, stream>>>(x, 1, wt, q1, k1, xw, sq, sk, N, dflag);
  aggregate_kernel<<<nodes4, 256, 0, stream>>>(rowptr, key, attrp, sq, sk, xw, b1,
                                               cscal + 0, hbuf, N, 1, 0, dflag);

  // ---- conv2 ----
  transpose_w_kernel<<<(R * 2048 + 255) / 256, 256, 0, stream>>>(w2, wt, R * 2048, dflag);
  gemm_xw_kernel<<<ggrid, 256, 0, stream>>>(hbuf, 0, wt, q2, k2, xw, sq, sk, N, dflag);
  aggregate_kernel<<<nodes4, 256, 0, stream>>>(rowptr, key, attrp, sq, sk, xw, b2,
                                               cscal + 1, d_out, N, 0, 1, dflag);
}

// Round 4
// 287.126 us; speedup vs baseline: 1.2984x; 1.2984x over previous
//
#include <hip/hip_runtime.h>
#include <hip/hip_bf16.h>
#include <math.h>

typedef __bf16 bf16x8 __attribute__((ext_vector_type(8)));
typedef float f32x4 __attribute__((ext_vector_type(4)));

#define CDIM 128
#define ECAP 128   // per-node LDS edge cache (deg>ECAP falls back to recompute)

__global__ void sentinel_kernel(float* outf) {
  if (threadIdx.x == 0) outf[0] = 12345.0f;  // ws_size too small signature
}

// ---------------- small utility kernels ----------------

__global__ __launch_bounds__(128) void consts_kernel(
    const float* __restrict__ le1, const float* __restrict__ e1,
    const float* __restrict__ le2, const float* __restrict__ e2,
    float* __restrict__ outc) {
  __shared__ float s1[CDIM], s2[CDIM];
  int t = threadIdx.x;
  s1[t] = le1[t] * e1[t];
  s2[t] = le2[t] * e2[t];
  __syncthreads();
  for (int off = 64; off > 0; off >>= 1) {
    if (t < off) { s1[t] += s1[t + off]; s2[t] += s2[t + off]; }
    __syncthreads();
  }
  if (t == 0) { outc[0] = s1[0]; outc[1] = s2[0]; }
}

__global__ __launch_bounds__(256) void hist_kernel(const int* __restrict__ dstv,
                                                   int* __restrict__ deg, int E) {
  int e = blockIdx.x * 256 + threadIdx.x;
  if (e < E) atomicAdd(&deg[dstv[e]], 1);
}

__global__ __launch_bounds__(256) void scan1_kernel(const int* __restrict__ deg,
                                                    int* __restrict__ rowptr,
                                                    int* __restrict__ partials, int n) {
  __shared__ int sh[256];
  int t = threadIdx.x;
  int base = blockIdx.x * 1024;
  int idx = base + t * 4;
  int v[4]; int s = 0;
#pragma unroll
  for (int j = 0; j < 4; ++j) { v[j] = (idx + j < n) ? deg[idx + j] : 0; s += v[j]; }
  sh[t] = s;
  __syncthreads();
  for (int off = 1; off < 256; off <<= 1) {
    int x = (t >= off) ? sh[t - off] : 0;
    __syncthreads();
    sh[t] += x;
    __syncthreads();
  }
  int excl = sh[t] - s;
  if (t == 255) partials[blockIdx.x] = sh[255];
  int run = excl;
#pragma unroll
  for (int j = 0; j < 4; ++j) {
    if (idx + j < n) rowptr[idx + j] = run;
    run += v[j];
  }
}

__global__ void scan2_kernel(int* __restrict__ partials, int nb) {
  if (threadIdx.x == 0 && blockIdx.x == 0) {
    int run = 0;
    for (int i = 0; i < nb; ++i) { int t = partials[i]; partials[i] = run; run += t; }
  }
}

__global__ __launch_bounds__(256) void scan3_kernel(int* __restrict__ rowptr,
                                                    int* __restrict__ cursor,
                                                    const int* __restrict__ partials,
                                                    int n, int E) {
  int i = blockIdx.x * 256 + threadIdx.x;
  if (i < n) {
    int v = rowptr[i] + partials[i >> 10];
    rowptr[i] = v;
    cursor[i] = v;
  } else if (i == n) {
    rowptr[n] = E;
  }
}

// counting-sort into CSR order; pack (key, attr) as int2 for one-load access
__global__ __launch_bounds__(256) void scatter_kernel(
    const int* __restrict__ srcv, const int* __restrict__ dstv,
    const int* __restrict__ etype, const float* __restrict__ eattr,
    int* __restrict__ cursor, int2* __restrict__ kattr, int E, int n) {
  int e = blockIdx.x * 256 + threadIdx.x;
  if (e >= E) return;
  int p = atomicAdd(&cursor[dstv[e]], 1);
  kattr[p] = make_int2(etype[e] * n + srcv[e], __float_as_int(eattr[e]));
}

// wt[r][kb][o][j] = w[r][kb*8+j][o]  (B^T tile layout for MFMA b-frags), f32 -> bf16
__global__ __launch_bounds__(256) void transpose_w_kernel(
    const float* __restrict__ w, __hip_bfloat16* __restrict__ wt, int total) {
  int t = blockIdx.x * 256 + threadIdx.x;
  if (t >= total) return;            // total = R*16*128
  int r = t >> 11;
  int rem = t & 2047;
  int kb = rem >> 7;
  int o = rem & 127;
  const float* wr = w + ((size_t)r << 14);
  union { __hip_bfloat16 h[8]; int4 v; } u;
#pragma unroll
  for (int j = 0; j < 8; ++j)
    u.h[j] = __float2bfloat16(wr[(size_t)(kb * 8 + j) * CDIM + o]);
  *reinterpret_cast<int4*>(wt + (size_t)t * 8) = u.v;
}

// ---------------- GEMM: xw[r] = xin @ w[r]; also sq[r,n]=xw.q, sk[r,n]=xw.k ----
__global__ __launch_bounds__(256) void gemm_xw_kernel(
    const float* __restrict__ xin, const __hip_bfloat16* __restrict__ wt,
    const float* __restrict__ qv, const float* __restrict__ kv,
    __hip_bfloat16* __restrict__ xwout, float* __restrict__ sq, float* __restrict__ sk,
    int n) {
  __shared__ __hip_bfloat16 wlds[16 * 128 * 8];  // 32 KB
  const int r = blockIdx.y;
  const int base = blockIdx.x * 128;
  const int tid = threadIdx.x;
  {
    const int4* src = reinterpret_cast<const int4*>(wt + ((size_t)r << 14));
    int4* dst = reinterpret_cast<int4*>(wlds);
    for (int i = tid; i < 2048; i += 256) dst[i] = src[i];
  }
  __syncthreads();

  const int wave = tid >> 6, lane = tid & 63;
  const int quad = lane >> 4, c16 = lane & 15;

  bf16x8 zf;
#pragma unroll
  for (int j = 0; j < 8; ++j) zf[j] = (__bf16)0.0f;

  bf16x8 af[2][4];
#pragma unroll
  for (int h = 0; h < 2; ++h) {
    int m = base + wave * 32 + h * 16 + c16;
#pragma unroll
    for (int ks = 0; ks < 4; ++ks) {
      if (m < n) {
        const float* xp = xin + (size_t)m * CDIM + ks * 32 + quad * 8;
        f32x4 x0 = *reinterpret_cast<const f32x4*>(xp);
        f32x4 x1 = *reinterpret_cast<const f32x4*>(xp + 4);
        bf16x8 a;
#pragma unroll
        for (int j = 0; j < 4; ++j) { a[j] = (__bf16)x0[j]; a[4 + j] = (__bf16)x1[j]; }
        af[h][ks] = a;
      } else {
        af[h][ks] = zf;
      }
    }
  }

  f32x4 acc[2][8];
#pragma unroll
  for (int h = 0; h < 2; ++h)
#pragma unroll
    for (int nt = 0; nt < 8; ++nt) acc[h][nt] = (f32x4){0.f, 0.f, 0.f, 0.f};

#pragma unroll
  for (int ks = 0; ks < 4; ++ks) {
#pragma unroll
    for (int nt = 0; nt < 8; ++nt) {
      bf16x8 b = *reinterpret_cast<const bf16x8*>(
          &wlds[(((ks * 4 + quad) * 128) + nt * 16 + c16) * 8]);
      acc[0][nt] = __builtin_amdgcn_mfma_f32_16x16x32_bf16(af[0][ks], b, acc[0][nt], 0, 0, 0);
      acc[1][nt] = __builtin_amdgcn_mfma_f32_16x16x32_bf16(af[1][ks], b, acc[1][nt], 0, 0, 0);
    }
  }

  float qf[8], kf[8];
#pragma unroll
  for (int nt = 0; nt < 8; ++nt) {
    qf[nt] = qv[nt * 16 + c16];
    kf[nt] = kv[nt * 16 + c16];
  }

#pragma unroll
  for (int h = 0; h < 2; ++h) {
    int rowb = base + wave * 32 + h * 16 + quad * 4;
#pragma unroll
    for (int reg = 0; reg < 4; ++reg) {
      int grow = rowb + reg;
      float s_q = 0.f, s_k = 0.f;
#pragma unroll
      for (int nt = 0; nt < 8; ++nt) {
        float v = acc[h][nt][reg];
        if (grow < n)
          xwout[(((size_t)r * n + grow) << 7) + nt * 16 + c16] = __float2bfloat16(v);
        s_q += v * qf[nt];
        s_k += v * kf[nt];
      }
#pragma unroll
      for (int off = 1; off < 16; off <<= 1) {
        s_q += __shfl_xor(s_q, off, 64);
        s_k += __shfl_xor(s_k, off, 64);
      }
      if (c16 == 0 && grow < n) {
        sq[r * n + grow] = s_q;
        sk[r * n + grow] = s_k;
      }
    }
  }
}

// ---------------- per-node softmax + aggregation: one wave64 per node ----------
// pass1 (lane-parallel): coalesced (key,attr) int2 load + sk gather -> logit; cache
// (kk, logit) in LDS; wave-reduce max. pass1.5: LDS logit -> exp weight.
// pass2 (serial): one ds_read_b64 + one 4B/lane bf16x2 feature load per edge.
__global__ __launch_bounds__(256) void aggregate_kernel(
    const int* __restrict__ rowptr, const int2* __restrict__ kattr,
    const float* __restrict__ sq, const float* __restrict__ sk,
    const __hip_bfloat16* __restrict__ xw, const float* __restrict__ bias,
    const float* __restrict__ cscal, float* __restrict__ out, int n, int do_relu) {
  __shared__ int2 ldsE[4][ECAP];   // x = kk, y = logit/weight bits
  const int wave = threadIdx.x >> 6, lane = threadIdx.x & 63;
  const int node = blockIdx.x * 4 + wave;
  const bool active = node < n;
  const float c = cscal[0];
  const int n2 = n * 2, n3 = n * 3;

  int start = 0, deg = 0;
  float s0 = 0.f, s1 = 0.f, s2 = 0.f;
  if (active) {
    start = rowptr[node];
    deg = rowptr[node + 1] - start;
    s0 = sq[node]; s1 = sq[n + node]; s2 = sq[n2 + node];
  }

  // pass 1: lane-parallel logits + max
  float m = -__builtin_inff();
  if (active) {
    for (int j = lane; j < deg; j += 64) {
      int2 ka = kattr[start + j];
      int kk = ka.x;
      kk = (kk < 0) ? 0 : (kk >= n3 ? n3 - 1 : kk);
      float sv = (kk >= n2) ? s2 : ((kk >= n) ? s1 : s0);
      float l = sv + sk[kk] + c * __int_as_float(ka.y);
      l = l > 0.f ? l : 0.2f * l;
      if (j < ECAP) ldsE[wave][j] = make_int2(kk, __float_as_int(l));
      m = fmaxf(m, l);
    }
  }
#pragma unroll
  for (int off = 32; off > 0; off >>= 1) m = fmaxf(m, __shfl_xor(m, off, 64));
  __syncthreads();

  // pass 1.5: logits -> exp weights (in LDS)
  const int cap = deg < ECAP ? deg : ECAP;
  if (active) {
    for (int i = lane; i < cap; i += 64) {
      int2 e = ldsE[wave][i];
      e.y = __float_as_int(__expf(__int_as_float(e.y) - m));
      ldsE[wave][i] = e;
    }
  }
  __syncthreads();

  // pass 2: serial weighted gather; each lane covers cols (2*lane, 2*lane+1)
  float a0 = 0.f, a1 = 0.f, den = 0.f;
  if (active) {
    for (int j = 0; j < cap; ++j) {
      int2 e = ldsE[wave][j];
      float w = __int_as_float(e.y);
      __hip_bfloat162 f01 =
          *reinterpret_cast<const __hip_bfloat162*>(xw + ((size_t)e.x << 7) + lane * 2);
      float2 ff = __bfloat1622float2(f01);
      a0 += w * ff.x;
      a1 += w * ff.y;
      den += w;
    }
    // overflow fallback (deg > ECAP): recompute inline (rare/never for this graph)
    for (int j = cap; j < deg; ++j) {
      int2 ka = kattr[start + j];
      int kk = ka.x;
      kk = (kk < 0) ? 0 : (kk >= n3 ? n3 - 1 : kk);
      float sv = (kk >= n2) ? s2 : ((kk >= n) ? s1 : s0);
      float l = sv + sk[kk] + c * __int_as_float(ka.y);
      l = l > 0.f ? l : 0.2f * l;
      float w = __expf(l - m);
      __hip_bfloat162 f01 =
          *reinterpret_cast<const __hip_bfloat162*>(xw + ((size_t)kk << 7) + lane * 2);
      float2 ff = __bfloat1622float2(f01);
      a0 += w * ff.x;
      a1 += w * ff.y;
      den += w;
    }
    float inv = 1.0f / (den + 1e-16f);
    float2 bb = *reinterpret_cast<const float2*>(bias + lane * 2);
    float o0 = a0 * inv + bb.x;
    float o1 = a1 * inv + bb.y;
    if (do_relu) { o0 = fmaxf(o0, 0.f); o1 = fmaxf(o1, 0.f); }
    *reinterpret_cast<float2*>(out + (size_t)node * CDIM + lane * 2) =
        make_float2(o0, o1);
  }
}

// ---------------- launcher ----------------

extern "C" void kernel_launch(void* const* d_in, const int* in_sizes, int n_in,
                              void* d_out, int out_size, void* d_ws, size_t ws_size,
                              hipStream_t stream) {
  const float* x     = (const float*)d_in[0];
  const int*   eidx  = (const int*)d_in[1];
  const int*   etype = (const int*)d_in[2];
  const float* eattr = (const float*)d_in[3];
  const float* w1  = (const float*)d_in[4];
  const float* q1  = (const float*)d_in[5];
  const float* k1  = (const float*)d_in[6];
  const float* le1 = (const float*)d_in[7];
  const float* e1  = (const float*)d_in[8];
  const float* b1  = (const float*)d_in[9];
  const float* w2  = (const float*)d_in[10];
  const float* q2  = (const float*)d_in[11];
  const float* k2  = (const float*)d_in[12];
  const float* le2 = (const float*)d_in[13];
  const float* e2  = (const float*)d_in[14];
  const float* b2  = (const float*)d_in[15];

  const int N = in_sizes[0] / CDIM;           // 50000
  const int E = in_sizes[2];                  // 500000
  const int R = in_sizes[4] / (CDIM * CDIM);  // 3
  const int* srcv = eidx;
  const int* dstv = eidx + E;

  // ---- workspace partition ----
  char* p = (char*)d_ws;
  auto alloc = [&](size_t bytes) -> void* {
    void* q = (void*)p;
    p += (bytes + 255) & ~(size_t)255;
    return q;
  };
  float* sq       = (float*)alloc((size_t)R * N * 4);
  float* sk       = (float*)alloc((size_t)R * N * 4);
  int*   deg      = (int*)alloc((size_t)N * 4);
  int*   rowptr   = (int*)alloc((size_t)(N + 1) * 4);
  int*   cursor   = (int*)alloc((size_t)N * 4);
  int*   partials = (int*)alloc(4096);
  int2*  kattr    = (int2*)alloc((size_t)E * 8);
  __hip_bfloat16* wt = (__hip_bfloat16*)alloc((size_t)R * CDIM * CDIM * 2);
  float* cscal    = (float*)alloc(256);
  __hip_bfloat16* xw = (__hip_bfloat16*)alloc((size_t)R * N * CDIM * 2);

  size_t needed = (size_t)(p - (char*)d_ws);
  if (needed > ws_size) {
    sentinel_kernel<<<1, 64, 0, stream>>>((float*)d_out);
    return;
  }

  float* outp = (float*)d_out;
  float* hbuf = outp;  // conv1 hidden (f32) lives in d_out; dead before final write

  const int eg = (E + 255) / 256;
  const int nb = (N + 1023) / 1024;
  const int nodes4 = (N + 3) / 4;

  consts_kernel<<<1, 128, 0, stream>>>(le1, e1, le2, e2, cscal);

  // CSR build (shared by both convs)
  hipMemsetAsync(deg, 0, (size_t)N * 4, stream);
  hist_kernel<<<eg, 256, 0, stream>>>(dstv, deg, E);
  scan1_kernel<<<nb, 256, 0, stream>>>(deg, rowptr, partials, N);
  scan2_kernel<<<1, 64, 0, stream>>>(partials, nb);
  scan3_kernel<<<(N + 1 + 255) / 256, 256, 0, stream>>>(rowptr, cursor, partials, N, E);
  scatter_kernel<<<eg, 256, 0, stream>>>(srcv, dstv, etype, eattr, cursor, kattr, E, N);

  dim3 ggrid((N + 127) / 128, R);

  // ---- conv1 ----
  transpose_w_kernel<<<(R * 2048 + 255) / 256, 256, 0, stream>>>(w1, wt, R * 2048);
  gemm_xw_kernel<<<ggrid, 256, 0, stream>>>(x, wt, q1, k1, xw, sq, sk, N);
  aggregate_kernel<<<nodes4, 256, 0, stream>>>(rowptr, kattr, sq, sk, xw, b1,
                                               cscal + 0, hbuf, N, 1);

  // ---- conv2 ----
  transpose_w_kernel<<<(R * 2048 + 255) / 256, 256, 0, stream>>>(w2, wt, R * 2048);
  gemm_xw_kernel<<<ggrid, 256, 0, stream>>>(hbuf, wt, q2, k2, xw, sq, sk, N);
  aggregate_kernel<<<nodes4, 256, 0, stream>>>(rowptr, kattr, sq, sk, xw, b2,
                                               cscal + 1, outp, N, 0);
}

// Round 5
// 279.212 us; speedup vs baseline: 1.3352x; 1.0283x over previous
//
#include <hip/hip_runtime.h>
#include <hip/hip_bf16.h>
#include <math.h>

typedef __bf16 bf16x8 __attribute__((ext_vector_type(8)));
typedef float f32x4 __attribute__((ext_vector_type(4)));

#define CDIM 128
#define ECAP 192   // per-node LDS edge cache (deg>ECAP -> recompute fallback)

__global__ void sentinel_kernel(float* outf) {
  if (threadIdx.x == 0) outf[0] = 12345.0f;  // ws_size too small signature
}

// ---------------- prep: transpose w1,w2 -> bf16 B^T tiles + consts ----------
// wt[v][r][kb][o][j] = w_v[r][kb*8+j][o];  last block computes c = le.e
__global__ __launch_bounds__(256) void prep_kernel(
    const float* __restrict__ w1, const float* __restrict__ w2,
    __hip_bfloat16* __restrict__ wt,
    const float* __restrict__ le1, const float* __restrict__ e1,
    const float* __restrict__ le2, const float* __restrict__ e2,
    float* __restrict__ outc, int perW) {
  if (blockIdx.x == gridDim.x - 1) {
    __shared__ float s1[128], s2[128];
    int t = threadIdx.x;
    if (t < 128) { s1[t] = le1[t] * e1[t]; s2[t] = le2[t] * e2[t]; }
    __syncthreads();
    for (int off = 64; off > 0; off >>= 1) {
      if (t < off) { s1[t] += s1[t + off]; s2[t] += s2[t + off]; }
      __syncthreads();
    }
    if (t == 0) { outc[0] = s1[0]; outc[1] = s2[0]; }
    return;
  }
  int t = blockIdx.x * 256 + threadIdx.x;
  if (t >= perW * 2) return;
  const float* w = (t < perW) ? w1 : w2;
  int tt = (t < perW) ? t : t - perW;
  int r = tt >> 11;
  int rem = tt & 2047;
  int kb = rem >> 7;
  int o = rem & 127;
  const float* wr = w + ((size_t)r << 14);
  union { __hip_bfloat16 h[8]; int4 v; } u;
#pragma unroll
  for (int j = 0; j < 8; ++j)
    u.h[j] = __float2bfloat16(wr[(size_t)(kb * 8 + j) * CDIM + o]);
  *reinterpret_cast<int4*>(wt + (size_t)t * 8) = u.v;
}

// ---------------- CSR build ----------------

__global__ __launch_bounds__(256) void hist_kernel(const int* __restrict__ dstv,
                                                   int* __restrict__ deg, int E) {
  int e = blockIdx.x * 256 + threadIdx.x;
  if (e < E) atomicAdd(&deg[dstv[e]], 1);
}

__global__ __launch_bounds__(256) void scan1_kernel(const int* __restrict__ deg,
                                                    int* __restrict__ rowptr,
                                                    int* __restrict__ partials, int n) {
  __shared__ int sh[256];
  int t = threadIdx.x;
  int base = blockIdx.x * 1024;
  int idx = base + t * 4;
  int v[4]; int s = 0;
#pragma unroll
  for (int j = 0; j < 4; ++j) { v[j] = (idx + j < n) ? deg[idx + j] : 0; s += v[j]; }
  sh[t] = s;
  __syncthreads();
  for (int off = 1; off < 256; off <<= 1) {
    int x = (t >= off) ? sh[t - off] : 0;
    __syncthreads();
    sh[t] += x;
    __syncthreads();
  }
  int excl = sh[t] - s;
  if (t == 255) partials[blockIdx.x] = sh[255];
  int run = excl;
#pragma unroll
  for (int j = 0; j < 4; ++j) {
    if (idx + j < n) rowptr[idx + j] = run;
    run += v[j];
  }
}

// parallel exclusive scan of block partials (single 256-thr block, carry loop)
__global__ __launch_bounds__(256) void scan2_kernel(int* __restrict__ partials, int nb) {
  __shared__ int sh[256];
  int carry = 0;
  for (int base = 0; base < nb; base += 256) {
    int i = base + threadIdx.x;
    int v = (i < nb) ? partials[i] : 0;
    sh[threadIdx.x] = v;
    __syncthreads();
    for (int off = 1; off < 256; off <<= 1) {
      int x = (threadIdx.x >= off) ? sh[threadIdx.x - off] : 0;
      __syncthreads();
      sh[threadIdx.x] += x;
      __syncthreads();
    }
    if (i < nb) partials[i] = carry + sh[threadIdx.x] - v;
    carry += sh[255];
    __syncthreads();
  }
}

__global__ __launch_bounds__(256) void scan3_kernel(int* __restrict__ rowptr,
                                                    int* __restrict__ cursor,
                                                    const int* __restrict__ partials,
                                                    int n, int E) {
  int i = blockIdx.x * 256 + threadIdx.x;
  if (i < n) {
    int v = rowptr[i] + partials[i >> 10];
    rowptr[i] = v;
    cursor[i] = v;
  } else if (i == n) {
    rowptr[n] = E;
  }
}

// counting-sort into CSR order; pack (key, attr) as int2 for one-load access
__global__ __launch_bounds__(256) void scatter_kernel(
    const int* __restrict__ srcv, const int* __restrict__ dstv,
    const int* __restrict__ etype, const float* __restrict__ eattr,
    int* __restrict__ cursor, int2* __restrict__ kattr, int E, int n) {
  int e = blockIdx.x * 256 + threadIdx.x;
  if (e >= E) return;
  int p = atomicAdd(&cursor[dstv[e]], 1);
  kattr[p] = make_int2(etype[e] * n + srcv[e], __float_as_int(eattr[e]));
}

// ---------------- GEMM: xw[r] = xin @ w[r]; also sq[r,n]=xw.q, sk[r,n]=xw.k ----
__global__ __launch_bounds__(256) void gemm_xw_kernel(
    const float* __restrict__ xin, const __hip_bfloat16* __restrict__ wt,
    const float* __restrict__ qv, const float* __restrict__ kv,
    __hip_bfloat16* __restrict__ xwout, float* __restrict__ sq, float* __restrict__ sk,
    int n) {
  __shared__ __hip_bfloat16 wlds[16 * 128 * 8];  // 32 KB
  const int r = blockIdx.y;
  const int base = blockIdx.x * 128;
  const int tid = threadIdx.x;
  {
    const int4* src = reinterpret_cast<const int4*>(wt + ((size_t)r << 14));
    int4* dst = reinterpret_cast<int4*>(wlds);
    for (int i = tid; i < 2048; i += 256) dst[i] = src[i];
  }
  __syncthreads();

  const int wave = tid >> 6, lane = tid & 63;
  const int quad = lane >> 4, c16 = lane & 15;

  bf16x8 zf;
#pragma unroll
  for (int j = 0; j < 8; ++j) zf[j] = (__bf16)0.0f;

  bf16x8 af[2][4];
#pragma unroll
  for (int h = 0; h < 2; ++h) {
    int m = base + wave * 32 + h * 16 + c16;
#pragma unroll
    for (int ks = 0; ks < 4; ++ks) {
      if (m < n) {
        const float* xp = xin + (size_t)m * CDIM + ks * 32 + quad * 8;
        f32x4 x0 = *reinterpret_cast<const f32x4*>(xp);
        f32x4 x1 = *reinterpret_cast<const f32x4*>(xp + 4);
        bf16x8 a;
#pragma unroll
        for (int j = 0; j < 4; ++j) { a[j] = (__bf16)x0[j]; a[4 + j] = (__bf16)x1[j]; }
        af[h][ks] = a;
      } else {
        af[h][ks] = zf;
      }
    }
  }

  f32x4 acc[2][8];
#pragma unroll
  for (int h = 0; h < 2; ++h)
#pragma unroll
    for (int nt = 0; nt < 8; ++nt) acc[h][nt] = (f32x4){0.f, 0.f, 0.f, 0.f};

#pragma unroll
  for (int ks = 0; ks < 4; ++ks) {
#pragma unroll
    for (int nt = 0; nt < 8; ++nt) {
      bf16x8 b = *reinterpret_cast<const bf16x8*>(
          &wlds[(((ks * 4 + quad) * 128) + nt * 16 + c16) * 8]);
      acc[0][nt] = __builtin_amdgcn_mfma_f32_16x16x32_bf16(af[0][ks], b, acc[0][nt], 0, 0, 0);
      acc[1][nt] = __builtin_amdgcn_mfma_f32_16x16x32_bf16(af[1][ks], b, acc[1][nt], 0, 0, 0);
    }
  }

  float qf[8], kf[8];
#pragma unroll
  for (int nt = 0; nt < 8; ++nt) {
    qf[nt] = qv[nt * 16 + c16];
    kf[nt] = kv[nt * 16 + c16];
  }

#pragma unroll
  for (int h = 0; h < 2; ++h) {
    int rowb = base + wave * 32 + h * 16 + quad * 4;
#pragma unroll
    for (int reg = 0; reg < 4; ++reg) {
      int grow = rowb + reg;
      float s_q = 0.f, s_k = 0.f;
#pragma unroll
      for (int nt = 0; nt < 8; ++nt) {
        float v = acc[h][nt][reg];
        if (grow < n)
          xwout[(((size_t)r * n + grow) << 7) + nt * 16 + c16] = __float2bfloat16(v);
        s_q += v * qf[nt];
        s_k += v * kf[nt];
      }
#pragma unroll
      for (int off = 1; off < 16; off <<= 1) {
        s_q += __shfl_xor(s_q, off, 64);
        s_k += __shfl_xor(s_k, off, 64);
      }
      if (c16 == 0 && grow < n) {
        sq[r * n + grow] = s_q;
        sk[r * n + grow] = s_k;
      }
    }
  }
}

// ---------------- per-node softmax + aggregation: one wave64 per node ----------
// pass1: lane-parallel logits -> LDS cache + wave max. pass1.5: exp in LDS.
// pass2: 4 edge-groups x 16 lanes; each lane loads bf16x8 (16B) of the row;
//        cross-group shfl_xor(16/32) reduction; 16 lanes store float4 x2.
__global__ __launch_bounds__(256) void aggregate_kernel(
    const int* __restrict__ rowptr, const int2* __restrict__ kattr,
    const float* __restrict__ sq, const float* __restrict__ sk,
    const __hip_bfloat16* __restrict__ xw, const float* __restrict__ bias,
    const float* __restrict__ cscal, float* __restrict__ out, int n, int do_relu) {
  __shared__ int2 ldsE[4][ECAP];   // x = kk, y = logit/weight bits
  const int wave = threadIdx.x >> 6, lane = threadIdx.x & 63;
  const int node = blockIdx.x * 4 + wave;
  const bool active = node < n;
  const float c = cscal[0];
  const int n2 = n * 2;

  int start = 0, deg = 0;
  float s0 = 0.f, s1 = 0.f, s2 = 0.f;
  if (active) {
    start = rowptr[node];
    deg = rowptr[node + 1] - start;
    s0 = sq[node]; s1 = sq[n + node]; s2 = sq[n2 + node];
  }

  // pass 1: lane-parallel logits + max
  float m = -__builtin_inff();
  if (active) {
    for (int j = lane; j < deg; j += 64) {
      int2 ka = kattr[start + j];
      int kk = ka.x;
      float sv = (kk >= n2) ? s2 : ((kk >= n) ? s1 : s0);
      float l = sv + sk[kk] + c * __int_as_float(ka.y);
      l = l > 0.f ? l : 0.2f * l;
      if (j < ECAP) ldsE[wave][j] = make_int2(kk, __float_as_int(l));
      m = fmaxf(m, l);
    }
  }
#pragma unroll
  for (int off = 32; off > 0; off >>= 1) m = fmaxf(m, __shfl_xor(m, off, 64));
  __syncthreads();

  // pass 1.5: logits -> exp weights (in LDS)
  const int cap = deg < ECAP ? deg : ECAP;
  if (active) {
    for (int i = lane; i < cap; i += 64) {
      int2 e = ldsE[wave][i];
      e.y = __float_as_int(__expf(__int_as_float(e.y) - m));
      ldsE[wave][i] = e;
    }
  }
  __syncthreads();

  // pass 2: grouped gather
  const int g = lane >> 4;     // edge group
  const int sub = lane & 15;   // 8-col chunk
  float acc[8];
#pragma unroll
  for (int t = 0; t < 8; ++t) acc[t] = 0.f;
  float den = 0.f;

  if (active) {
    for (int j0 = 0; j0 < cap; j0 += 4) {
      int j = j0 + g;
      float w = 0.f; int kk = 0;
      if (j < cap) {
        int2 e = ldsE[wave][j];
        kk = e.x;
        w = __int_as_float(e.y);
      }
      bf16x8 f = *reinterpret_cast<const bf16x8*>(xw + ((size_t)kk << 7) + sub * 8);
#pragma unroll
      for (int t = 0; t < 8; ++t) acc[t] += w * (float)f[t];
      den += w;
    }
    // overflow fallback (deg > ECAP): recompute weights from global
    for (int j0 = cap; j0 < deg; j0 += 4) {
      int j = j0 + g;
      float w = 0.f; int kk = 0;
      if (j < deg) {
        int2 ka = kattr[start + j];
        kk = ka.x;
        float sv = (kk >= n2) ? s2 : ((kk >= n) ? s1 : s0);
        float l = sv + sk[kk] + c * __int_as_float(ka.y);
        l = l > 0.f ? l : 0.2f * l;
        w = __expf(l - m);
      }
      bf16x8 f = *reinterpret_cast<const bf16x8*>(xw + ((size_t)kk << 7) + sub * 8);
#pragma unroll
      for (int t = 0; t < 8; ++t) acc[t] += w * (float)f[t];
      den += w;
    }

    // cross-group reduction (lanes sub, sub+16, sub+32, sub+48)
#pragma unroll
    for (int t = 0; t < 8; ++t) {
      acc[t] += __shfl_xor(acc[t], 16, 64);
      acc[t] += __shfl_xor(acc[t], 32, 64);
    }
    den += __shfl_xor(den, 16, 64);
    den += __shfl_xor(den, 32, 64);

    if (g == 0) {
      float inv = 1.0f / (den + 1e-16f);
      f32x4 b0 = *reinterpret_cast<const f32x4*>(bias + sub * 8);
      f32x4 b1 = *reinterpret_cast<const f32x4*>(bias + sub * 8 + 4);
      f32x4 o0, o1;
#pragma unroll
      for (int t = 0; t < 4; ++t) {
        o0[t] = acc[t] * inv + b0[t];
        o1[t] = acc[4 + t] * inv + b1[t];
      }
      if (do_relu) {
#pragma unroll
        for (int t = 0; t < 4; ++t) {
          o0[t] = fmaxf(o0[t], 0.f);
          o1[t] = fmaxf(o1[t], 0.f);
        }
      }
      float* op = out + (size_t)node * CDIM + sub * 8;
      *reinterpret_cast<f32x4*>(op) = o0;
      *reinterpret_cast<f32x4*>(op + 4) = o1;
    }
  }
}

// ---------------- launcher ----------------

extern "C" void kernel_launch(void* const* d_in, const int* in_sizes, int n_in,
                              void* d_out, int out_size, void* d_ws, size_t ws_size,
                              hipStream_t stream) {
  const float* x     = (const float*)d_in[0];
  const int*   eidx  = (const int*)d_in[1];
  const int*   etype = (const int*)d_in[2];
  const float* eattr = (const float*)d_in[3];
  const float* w1  = (const float*)d_in[4];
  const float* q1  = (const float*)d_in[5];
  const float* k1  = (const float*)d_in[6];
  const float* le1 = (const float*)d_in[7];
  const float* e1  = (const float*)d_in[8];
  const float* b1  = (const float*)d_in[9];
  const float* w2  = (const float*)d_in[10];
  const float* q2  = (const float*)d_in[11];
  const float* k2  = (const float*)d_in[12];
  const float* le2 = (const float*)d_in[13];
  const float* e2  = (const float*)d_in[14];
  const float* b2  = (const float*)d_in[15];

  const int N = in_sizes[0] / CDIM;           // 50000
  const int E = in_sizes[2];                  // 500000
  const int R = in_sizes[4] / (CDIM * CDIM);  // 3
  const int* srcv = eidx;
  const int* dstv = eidx + E;

  // ---- workspace partition ----
  char* p = (char*)d_ws;
  auto alloc = [&](size_t bytes) -> void* {
    void* q = (void*)p;
    p += (bytes + 255) & ~(size_t)255;
    return q;
  };
  float* sq       = (float*)alloc((size_t)R * N * 4);
  float* sk       = (float*)alloc((size_t)R * N * 4);
  int*   deg      = (int*)alloc((size_t)N * 4);
  int*   rowptr   = (int*)alloc((size_t)(N + 1) * 4);
  int*   cursor   = (int*)alloc((size_t)N * 4);
  int*   partials = (int*)alloc(4096);
  int2*  kattr    = (int2*)alloc((size_t)E * 8);
  __hip_bfloat16* wt = (__hip_bfloat16*)alloc((size_t)2 * R * CDIM * CDIM * 2);
  float* cscal    = (float*)alloc(256);
  __hip_bfloat16* xw = (__hip_bfloat16*)alloc((size_t)R * N * CDIM * 2);

  size_t needed = (size_t)(p - (char*)d_ws);
  if (needed > ws_size) {
    sentinel_kernel<<<1, 64, 0, stream>>>((float*)d_out);
    return;
  }

  float* outp = (float*)d_out;
  float* hbuf = outp;  // conv1 hidden (f32) lives in d_out; dead before final write

  const int eg = (E + 255) / 256;
  const int nb = (N + 1023) / 1024;
  const int nodes4 = (N + 3) / 4;
  const int perW = R * 2048;

  // prep: both weight transposes + consts (last block)
  prep_kernel<<<(perW * 2 + 255) / 256 + 1, 256, 0, stream>>>(
      w1, w2, wt, le1, e1, le2, e2, cscal, perW);

  // CSR build (shared by both convs)
  hipMemsetAsync(deg, 0, (size_t)N * 4, stream);
  hist_kernel<<<eg, 256, 0, stream>>>(dstv, deg, E);
  scan1_kernel<<<nb, 256, 0, stream>>>(deg, rowptr, partials, N);
  scan2_kernel<<<1, 256, 0, stream>>>(partials, nb);
  scan3_kernel<<<(N + 1 + 255) / 256, 256, 0, stream>>>(rowptr, cursor, partials, N, E);
  scatter_kernel<<<eg, 256, 0, stream>>>(srcv, dstv, etype, eattr, cursor, kattr, E, N);

  dim3 ggrid((N + 127) / 128, R);

  // ---- conv1 ----
  gemm_xw_kernel<<<ggrid, 256, 0, stream>>>(x, wt, q1, k1, xw, sq, sk, N);
  aggregate_kernel<<<nodes4, 256, 0, stream>>>(rowptr, kattr, sq, sk, xw, b1,
                                               cscal + 0, hbuf, N, 1);

  // ---- conv2 ----
  gemm_xw_kernel<<<ggrid, 256, 0, stream>>>(hbuf, wt + (size_t)R * CDIM * CDIM,
                                            q2, k2, xw, sq, sk, N);
  aggregate_kernel<<<nodes4, 256, 0, stream>>>(rowptr, kattr, sq, sk, xw, b2,
                                               cscal + 1, outp, N, 0);
}